// Round 10
// baseline (155.785 us; speedup 1.0000x reference)
//
#include <hip/hip_runtime.h>
#include <math.h>

// Problem constants
#define BATCH 64
#define SEQL  512
#define DIN   256
#define NF    256
#define KS    3
#define KF    (KS * NF)        // 768

// Fully fused combined-channel formulation, staging-free edition:
//   One block = (b, 64-row slab), 256 threads (4 waves), 2 blocks/CU.
//   LDS = 4 panels [66][128] bf16 only (x lo/hi, Y lo/hi) = 67.6 KB.
//   B-operands (WcT, UT) are L2-resident -> read DIRECTLY into registers
//   as MFMA fragments (16 B/lane); no global_load_lds, no staging buffers,
//   no per-region barriers. TWO __syncthreads() total. The two independent
//   blocks per CU cover each other's latency (m114 mechanism).
#define XCH 512
#define KC  (KS * XCH)          // 1536
#define PR2 66                  // 64 out rows + 2 halo
#define PLD 128                 // panel row stride in shorts (256 B)
#define P0SZ (PR2 * PLD)        // 8448 shorts per panel

typedef __attribute__((ext_vector_type(8))) short short8;
typedef __attribute__((ext_vector_type(4))) float floatx4;
typedef __attribute__((ext_vector_type(16))) float floatx16;
typedef __attribute__((ext_vector_type(8))) unsigned short ushort8v;
typedef __attribute__((ext_vector_type(4))) unsigned short ushort4v;

static __device__ __forceinline__ unsigned short f2bf(float f) {
    unsigned int u = __float_as_uint(f);
    return (unsigned short)((u + 0x7FFF + ((u >> 16) & 1)) >> 16);  // RTNE
}

// ---------------------------------------------------------------------------
// pack: WcT[f][c] transpose (96 blk), UT[e][d] transpose (16 blk).
// 112 blocks x 256 threads.
// ---------------------------------------------------------------------------
__global__ __launch_bounds__(256) void pack_kernel(
    const float* __restrict__ U, const float* __restrict__ V,
    const float* __restrict__ Bw,
    unsigned short* __restrict__ WcT, unsigned short* __restrict__ UT)
{
    const int blk = blockIdx.x;
    const int t   = threadIdx.x;
    __shared__ unsigned short tile[64][64 + 2];

    if (blk < 96) {
        const int f0 = (blk & 3) * 64, c0 = (blk >> 2) * 64;
        const int fl = t & 63, cb = t >> 6;
        #pragma unroll
        for (int it = 0; it < 16; ++it) {
            const int cl = cb + it * 4;
            const int c  = c0 + cl;
            const int k  = c >> 9, ch = c & (XCH - 1);
            const float v = (ch < DIN) ? Bw[(size_t)ch * KF + k * NF + f0 + fl]
                                       : V[(size_t)(ch - DIN) * KF + k * NF + f0 + fl];
            tile[cl][fl] = f2bf(v);
        }
        __syncthreads();
        const int cl2 = t & 63, fb = t >> 6;
        #pragma unroll
        for (int it = 0; it < 16; ++it) {
            const int fl2 = fb + it * 4;
            WcT[(size_t)(f0 + fl2) * KC + c0 + cl2] = tile[cl2][fl2];
        }
    } else {
        const int bb = blk - 96;
        const int e0 = (bb & 3) * 64, d0 = (bb >> 2) * 64;
        const int el = t & 63, db = t >> 6;
        #pragma unroll
        for (int it = 0; it < 16; ++it) {
            const int dl = db + it * 4;
            tile[dl][el] = f2bf(U[(size_t)(d0 + dl) * DIN + e0 + el]);
        }
        __syncthreads();
        const int dl2 = t & 63, eb = t >> 6;
        #pragma unroll
        for (int it = 0; it < 16; ++it) {
            const int el2 = eb + it * 4;
            UT[(size_t)(e0 + el2) * DIN + d0 + dl2] = tile[dl2][el2];
        }
    }
}

// ---------------------------------------------------------------------------
// fused kernel. Grid 512 x 256. LDS 67584 B -> 2 blocks/CU (8 waves/CU,
// two independent barrier domains).
// ---------------------------------------------------------------------------
__global__ __launch_bounds__(256, 2) void fused_kernel(
    const float* __restrict__ x, const float* __restrict__ z,
    const unsigned short* __restrict__ UT,
    const unsigned short* __restrict__ WcT,
    const float* __restrict__ bias, float* __restrict__ out)
{
    __shared__ __align__(16) unsigned short lds[4 * P0SZ];   // 67584 B

    const int tid  = threadIdx.x;
    const int lane = tid & 63;
    const int wave = tid >> 6;               // 0..3
    const int quad = lane >> 4, l16 = lane & 15;
    const int l32  = lane & 31, hi  = lane >> 5;

    const int bid = blockIdx.x;
    const int b   = bid >> 3;
    const int l0  = (bid & 7) * 64;

    // ---------------- phase X: x -> P0, P1 (bf16, swizzled) ----------------
    #pragma unroll
    for (int p = 0; p < 2; ++p) {
        unsigned short* P = lds + (size_t)p * P0SZ;
        #pragma unroll
        for (int it = 0; it < 5; ++it) {
            const int idx = tid + it * 256;
            if (idx < PR2 * 16) {
                const int row = idx >> 4, u = idx & 15;
                const int l = l0 - 1 + row;
                ushort8v h = {};
                if (l >= 0 && l < SEQL) {
                    const float* xp =
                        x + ((size_t)b * SEQL + l) * DIN + p * 128 + u * 8;
                    const float4 v0 = *(const float4*)xp;
                    const float4 v1 = *(const float4*)(xp + 4);
                    h[0] = f2bf(v0.x); h[1] = f2bf(v0.y);
                    h[2] = f2bf(v0.z); h[3] = f2bf(v0.w);
                    h[4] = f2bf(v1.x); h[5] = f2bf(v1.y);
                    h[6] = f2bf(v1.z); h[7] = f2bf(v1.w);
                }
                *(ushort8v*)&P[row * PLD + ((u ^ (row & 15)) << 3)] = h;
            }
        }
    }
    __syncthreads();                              // barrier 1 of 2

    // ---------------- phase G: Y = (x@U)*sigmoid(z), operand-swapped -------
    // accY = mfma(A = UT fragment from GLOBAL, B = x fragment from LDS).
    // D[e][xrow]: lane holds e = q*64+wave*16+quad*4+reg, xrow = i*16+l16.
    {
        floatx4 accY[4][5] = {};
        #pragma unroll 1
        for (int kk = 0; kk < 8; ++kk) {          // 32-d chunks
            const unsigned short* P = lds + (size_t)(kk >> 2) * P0SZ;
            const int ux = (kk & 3) * 4 + quad;   // panel d-unit
            short8 uf[4];
            #pragma unroll
            for (int q = 0; q < 4; ++q) {
                const int e = q * 64 + wave * 16 + l16;
                uf[q] = *(const short8*)
                    &UT[(size_t)e * DIN + kk * 32 + quad * 8];
            }
            #pragma unroll
            for (int i = 0; i < 5; ++i) {
                const int row = i * 16 + l16;     // rows>=66 garbage, masked
                const short8 xf = *(const short8*)
                    &P[row * PLD + ((ux ^ (row & 15)) << 3)];
                #pragma unroll
                for (int q = 0; q < 4; ++q)
                    accY[q][i] = __builtin_amdgcn_mfma_f32_16x16x32_bf16(
                        uf[q], xf, accY[q][i], 0, 0, 0);
            }
        }
        // Y epilogue: lane holds 4 consecutive e -> b64 writes into P2/P3.
        #pragma unroll
        for (int q = 0; q < 4; ++q) {
            const int e0 = q * 64 + wave * 16 + quad * 4;    // 0..252
            unsigned short* PY = lds + (size_t)(2 + (q >> 1)) * P0SZ;
            const int c0 = e0 & 127;
            float zf[4];
            #pragma unroll
            for (int r2 = 0; r2 < 4; ++r2)
                zf[r2] = 1.0f / (1.0f + expf(-z[(size_t)b * DIN + e0 + r2]));
            const int u = c0 >> 3;
            #pragma unroll
            for (int i = 0; i < 5; ++i) {
                const int xrow = i * 16 + l16;
                if (xrow < PR2) {
                    ushort4v h;
                    #pragma unroll
                    for (int r2 = 0; r2 < 4; ++r2)
                        h[r2] = f2bf(accY[q][i][r2] * zf[r2]);
                    *(ushort4v*)&PY[xrow * PLD + ((u ^ (xrow & 15)) << 3) +
                                    (c0 & 7)] = h;
                }
            }
        }
    }
    __syncthreads();                              // barrier 2 of 2

    // ---------------- conv: 4 panels x 3 taps, barrier-free ----------------
    // Per wave: 64 rows x 64 f. A from LDS panel, B from GLOBAL WcT
    // (L2-resident; 16 loads of a region hit the same 128-B lines -> L1).
    floatx16 acc2[2][2] = {};
    #pragma unroll 1
    for (int g = 0; g < 4; ++g) {
        const unsigned short* P = lds + (size_t)g * P0SZ;
        #pragma unroll 1
        for (int k = 0; k < KS; ++k) {
            const unsigned short* gW = WcT + (size_t)k * XCH + g * 128;
            #pragma unroll
            for (int ks = 0; ks < 8; ++ks) {      // K16 slices of 128 ch
                short8 af[2], bf[2];
                const int ua = ks * 2 + hi;
                #pragma unroll
                for (int i = 0; i < 2; ++i) {
                    const int m = i * 32 + l32 + k;          // 0..65
                    af[i] = *(const short8*)
                        &P[m * PLD + ((ua ^ (m & 15)) << 3)];
                }
                #pragma unroll
                for (int j = 0; j < 2; ++j) {
                    const int f = wave * 64 + j * 32 + l32;  // f row
                    bf[j] = *(const short8*)
                        &gW[(size_t)f * KC + ks * 16 + hi * 8];
                }
                #pragma unroll
                for (int i = 0; i < 2; ++i)
                    #pragma unroll
                    for (int j = 0; j < 2; ++j)
                        acc2[i][j] = __builtin_amdgcn_mfma_f32_32x32x16_bf16(
                            af[i], bf[j], acc2[i][j], 0, 0, 0);
            }
        }
    }

    // ---------------- epilogue: bias + relu -> out -------------------------
    #pragma unroll
    for (int j = 0; j < 2; ++j) {
        const int f  = wave * 64 + j * 32 + l32;
        const float bv = bias[f];
        #pragma unroll
        for (int i = 0; i < 2; ++i) {
            #pragma unroll
            for (int reg = 0; reg < 16; ++reg) {
                const int rowl = i * 32 + (reg & 3) + 8 * (reg >> 2) + 4 * hi;
                const float v = acc2[i][j][reg] + bv;
                out[((size_t)b * SEQL + l0 + rowl) * NF + f] = fmaxf(v, 0.0f);
            }
        }
    }
}

extern "C" void kernel_launch(void* const* d_in, const int* in_sizes, int n_in,
                              void* d_out, int out_size, void* d_ws, size_t ws_size,
                              hipStream_t stream) {
    const float* x    = (const float*)d_in[0];
    const float* z    = (const float*)d_in[1];
    const float* U    = (const float*)d_in[2];
    const float* V    = (const float*)d_in[3];
    const float* Bw   = (const float*)d_in[4];
    const float* bias = (const float*)d_in[5];

    unsigned short* WcT = (unsigned short*)d_ws;          // 256*1536*2 B
    unsigned short* UT  = WcT + (size_t)NF * KC;          // 256*256*2 B
    float* out = (float*)d_out;

    pack_kernel<<<dim3(112), 256, 0, stream>>>(U, V, Bw, WcT, UT);
    fused_kernel<<<dim3(512), 256, 0, stream>>>(x, z, UT, WcT, bias, out);
}

// Round 11
// 124.588 us; speedup vs baseline: 1.2504x; 1.2504x over previous
//
#include <hip/hip_runtime.h>
#include <math.h>

// Problem constants
#define BATCH 64
#define SEQL  512
#define DIN   256
#define NF    256
#define KS    3
#define KF    (KS * NF)        // 768

// Fully fused, staging-free, FRAGMENT-PACKED weights edition.
//   One block = (b, 64-row slab), 256 threads (4 waves), 2 blocks/CU,
//   LDS = 4 panels [66][128] bf16 = 67.6 KB, TWO barriers total.
//   Round-10 failure isolated: direct B-operand reads were gathers
//   (32 cache lines / wave instr -> ~8x L2 transaction amplification).
//   Fix: pack_kernel emits weights in MFMA-fragment order so every
//   B-fragment load is a coalesced 512B/32-lane stream:
//     WcTp[(g*3+k)][ks][f][c]  : c = 16 ch of the ks-slice   (786 KB)
//     UTp [kk][e][quad][c8]    : c8 = 8 d of the quad-slice  (128 KB)
#define XCH 512
#define KC  (KS * XCH)          // 1536
#define PR2 66                  // 64 out rows + 2 halo
#define PLD 128                 // panel row stride in shorts (256 B)
#define P0SZ (PR2 * PLD)        // 8448 shorts per panel

typedef __attribute__((ext_vector_type(8))) short short8;
typedef __attribute__((ext_vector_type(4))) float floatx4;
typedef __attribute__((ext_vector_type(16))) float floatx16;
typedef __attribute__((ext_vector_type(8))) unsigned short ushort8v;
typedef __attribute__((ext_vector_type(4))) unsigned short ushort4v;

static __device__ __forceinline__ unsigned short f2bf(float f) {
    unsigned int u = __float_as_uint(f);
    return (unsigned short)((u + 0x7FFF + ((u >> 16) & 1)) >> 16);  // RTNE
}

// ---------------------------------------------------------------------------
// pack: fragment-pack weights.
//   blocks 0..95 : WcTp. blk -> gk = blk>>3 (g*3+k), f-quarter = blk&7.
//     thread t: ks = t>>5, f = (blk&7)*32 + (t&31); writes 16 shorts.
//   blocks 96..111 : UTp. bb -> kk = bb>>1, e-half = bb&1.
//     thread t x2: p = t+it*256 -> e = e0 + (p>>2), quad = p&3; 8 shorts.
// ---------------------------------------------------------------------------
__global__ __launch_bounds__(256) void pack_kernel(
    const float* __restrict__ U, const float* __restrict__ V,
    const float* __restrict__ Bw,
    unsigned short* __restrict__ WcTp, unsigned short* __restrict__ UTp)
{
    const int blk = blockIdx.x;
    const int t   = threadIdx.x;

    if (blk < 96) {
        const int gk = blk >> 3;            // 0..11 = g*3 + k
        const int g  = gk / 3, k = gk % 3;
        const int ks = t >> 5;              // 0..7
        const int f  = (blk & 7) * 32 + (t & 31);
        unsigned short* dst = WcTp + ((size_t)(gk * 8 + ks) * 256 + f) * 16;
        #pragma unroll
        for (int c = 0; c < 16; ++c) {
            const int ch = g * 128 + ks * 16 + c;
            const float v = (ch < DIN)
                ? Bw[(size_t)ch * KF + k * NF + f]
                : V[(size_t)(ch - DIN) * KF + k * NF + f];
            dst[c] = f2bf(v);
        }
    } else {
        const int bb = blk - 96;            // 0..15
        const int kk = bb >> 1;             // 0..7
        const int e0 = (bb & 1) * 128;
        #pragma unroll
        for (int it = 0; it < 2; ++it) {
            const int p    = t + it * 256;  // 0..511
            const int e    = e0 + (p >> 2);
            const int quad = p & 3;
            unsigned short* dst =
                UTp + ((size_t)(kk * 256 + e) * 4 + quad) * 8;
            #pragma unroll
            for (int c = 0; c < 8; ++c) {
                const int d = kk * 32 + quad * 8 + c;
                dst[c] = f2bf(U[(size_t)d * DIN + e]);
            }
        }
    }
}

// ---------------------------------------------------------------------------
// fused kernel. Grid 512 x 256. LDS 67584 B -> 2 blocks/CU.
// ---------------------------------------------------------------------------
__global__ __launch_bounds__(256, 2) void fused_kernel(
    const float* __restrict__ x, const float* __restrict__ z,
    const unsigned short* __restrict__ UTp,
    const unsigned short* __restrict__ WcTp,
    const float* __restrict__ bias, float* __restrict__ out)
{
    __shared__ __align__(16) unsigned short lds[4 * P0SZ];   // 67584 B

    const int tid  = threadIdx.x;
    const int lane = tid & 63;
    const int wave = tid >> 6;               // 0..3
    const int quad = lane >> 4, l16 = lane & 15;
    const int l32  = lane & 31, hi  = lane >> 5;

    const int bid = blockIdx.x;
    const int b   = bid >> 3;
    const int l0  = (bid & 7) * 64;

    // ---------------- phase X: x -> P0, P1 (bf16, swizzled) ----------------
    #pragma unroll
    for (int p = 0; p < 2; ++p) {
        unsigned short* P = lds + (size_t)p * P0SZ;
        #pragma unroll
        for (int it = 0; it < 5; ++it) {
            const int idx = tid + it * 256;
            if (idx < PR2 * 16) {
                const int row = idx >> 4, u = idx & 15;
                const int l = l0 - 1 + row;
                ushort8v h = {};
                if (l >= 0 && l < SEQL) {
                    const float* xp =
                        x + ((size_t)b * SEQL + l) * DIN + p * 128 + u * 8;
                    const float4 v0 = *(const float4*)xp;
                    const float4 v1 = *(const float4*)(xp + 4);
                    h[0] = f2bf(v0.x); h[1] = f2bf(v0.y);
                    h[2] = f2bf(v0.z); h[3] = f2bf(v0.w);
                    h[4] = f2bf(v1.x); h[5] = f2bf(v1.y);
                    h[6] = f2bf(v1.z); h[7] = f2bf(v1.w);
                }
                *(ushort8v*)&P[row * PLD + ((u ^ (row & 15)) << 3)] = h;
            }
        }
    }
    __syncthreads();                              // barrier 1 of 2

    // ---------------- phase G: Y = (x@U)*sigmoid(z), operand-swapped -------
    // accY = mfma(A = UTp fragment from GLOBAL (coalesced), B = x from LDS).
    // D[e][xrow]: lane holds e = q*64+wave*16+quad*4+reg, xrow = i*16+l16.
    {
        floatx4 accY[4][5] = {};
        #pragma unroll 2
        for (int kk = 0; kk < 8; ++kk) {          // 32-d chunks
            const unsigned short* P = lds + (size_t)(kk >> 2) * P0SZ;
            const int ux = (kk & 3) * 4 + quad;   // panel d-unit
            short8 uf[4];
            #pragma unroll
            for (int q = 0; q < 4; ++q) {
                const int e = q * 64 + wave * 16 + l16;
                uf[q] = *(const short8*)
                    &UTp[((size_t)(kk * 256 + e) * 4 + quad) * 8];
            }
            #pragma unroll
            for (int i = 0; i < 5; ++i) {
                const int row = i * 16 + l16;     // rows>=66 garbage, masked
                const short8 xf = *(const short8*)
                    &P[row * PLD + ((ux ^ (row & 15)) << 3)];
                #pragma unroll
                for (int q = 0; q < 4; ++q)
                    accY[q][i] = __builtin_amdgcn_mfma_f32_16x16x32_bf16(
                        uf[q], xf, accY[q][i], 0, 0, 0);
            }
        }
        // Y epilogue: lane holds 4 consecutive e -> b64 writes into P2/P3.
        #pragma unroll
        for (int q = 0; q < 4; ++q) {
            const int e0 = q * 64 + wave * 16 + quad * 4;    // 0..252
            unsigned short* PY = lds + (size_t)(2 + (q >> 1)) * P0SZ;
            const int c0 = e0 & 127;
            float zf[4];
            #pragma unroll
            for (int r2 = 0; r2 < 4; ++r2)
                zf[r2] = 1.0f / (1.0f + expf(-z[(size_t)b * DIN + e0 + r2]));
            const int u = c0 >> 3;
            #pragma unroll
            for (int i = 0; i < 5; ++i) {
                const int xrow = i * 16 + l16;
                if (xrow < PR2) {
                    ushort4v h;
                    #pragma unroll
                    for (int r2 = 0; r2 < 4; ++r2)
                        h[r2] = f2bf(accY[q][i][r2] * zf[r2]);
                    *(ushort4v*)&PY[xrow * PLD + ((u ^ (xrow & 15)) << 3) +
                                    (c0 & 7)] = h;
                }
            }
        }
    }
    __syncthreads();                              // barrier 2 of 2

    // ---------------- conv: 4 panels x 3 taps, barrier-free ----------------
    // A from LDS panel; B from GLOBAL WcTp, fragment-packed -> coalesced
    // 512B/32-lane streams. g-loop start rotated by (bid&3) to decorrelate
    // co-resident blocks' L2 bursts.
    floatx16 acc2[2][2] = {};
    #pragma unroll 1
    for (int gg = 0; gg < 4; ++gg) {
        const int g = (gg + (bid & 3)) & 3;
        const unsigned short* P = lds + (size_t)g * P0SZ;
        #pragma unroll
        for (int k = 0; k < KS; ++k) {
            const unsigned short* gW =
                WcTp + (size_t)(g * 3 + k) * 8 * 4096;
            #pragma unroll
            for (int ks = 0; ks < 8; ++ks) {      // K16 slices of 128 ch
                short8 af[2], bf[2];
                const int ua = ks * 2 + hi;
                #pragma unroll
                for (int i = 0; i < 2; ++i) {
                    const int m = i * 32 + l32 + k;          // 0..65
                    af[i] = *(const short8*)
                        &P[m * PLD + ((ua ^ (m & 15)) << 3)];
                }
                #pragma unroll
                for (int j = 0; j < 2; ++j) {
                    const int f = wave * 64 + j * 32 + l32;  // f row
                    bf[j] = *(const short8*)
                        &gW[(size_t)ks * 4096 + (size_t)f * 16 + hi * 8];
                }
                #pragma unroll
                for (int i = 0; i < 2; ++i)
                    #pragma unroll
                    for (int j = 0; j < 2; ++j)
                        acc2[i][j] = __builtin_amdgcn_mfma_f32_32x32x16_bf16(
                            af[i], bf[j], acc2[i][j], 0, 0, 0);
            }
        }
    }

    // ---------------- epilogue: bias + relu -> out -------------------------
    #pragma unroll
    for (int j = 0; j < 2; ++j) {
        const int f  = wave * 64 + j * 32 + l32;
        const float bv = bias[f];
        #pragma unroll
        for (int i = 0; i < 2; ++i) {
            #pragma unroll
            for (int reg = 0; reg < 16; ++reg) {
                const int rowl = i * 32 + (reg & 3) + 8 * (reg >> 2) + 4 * hi;
                const float v = acc2[i][j][reg] + bv;
                out[((size_t)b * SEQL + l0 + rowl) * NF + f] = fmaxf(v, 0.0f);
            }
        }
    }
}

extern "C" void kernel_launch(void* const* d_in, const int* in_sizes, int n_in,
                              void* d_out, int out_size, void* d_ws, size_t ws_size,
                              hipStream_t stream) {
    const float* x    = (const float*)d_in[0];
    const float* z    = (const float*)d_in[1];
    const float* U    = (const float*)d_in[2];
    const float* V    = (const float*)d_in[3];
    const float* Bw   = (const float*)d_in[4];
    const float* bias = (const float*)d_in[5];

    unsigned short* WcTp = (unsigned short*)d_ws;            // 393216 shorts
    unsigned short* UTp  = WcTp + (size_t)12 * 8 * 256 * 16; // 65536 shorts
    float* out = (float*)d_out;

    pack_kernel<<<dim3(112), 256, 0, stream>>>(U, V, Bw, WcTp, UTp);
    fused_kernel<<<dim3(512), 256, 0, stream>>>(x, z, UTp, WcTp, bias, out);
}

// Round 12
// 121.664 us; speedup vs baseline: 1.2805x; 1.0240x over previous
//
#include <hip/hip_runtime.h>
#include <math.h>

// Problem constants
#define BATCH 64
#define SEQL  512
#define DIN   256
#define NF    256
#define KS    3
#define KF    (KS * NF)        // 768

// Fully fused, staging-free, fragment-packed weights + REGISTER PING-PONG:
//   One block = (b, 64-row slab), 256 threads (4 waves), 2 blocks/CU,
//   LDS = 4 panels [66][128] bf16 = 67.6 KB, TWO barriers total.
//   r11 was L2-latency-bound (VGPR 96 -> ~2 fragments in flight vs ~300cyc
//   L2 latency). Fix: explicit 1-region-ahead register double-buffering of
//   the B-streams (bA/bB 16 frags for conv, uA/uB 4 frags for G); first
//   loads issued early so latency hides under X / epilogue phases.
//     WcTp[(g*3+k)][ks][f][16ch]  coalesced fragment stream (786 KB)
//     UTp [kk][e][quad][8d]       coalesced fragment stream (128 KB)
#define XCH 512
#define KC  (KS * XCH)          // 1536
#define PR2 66                  // 64 out rows + 2 halo
#define PLD 128                 // panel row stride in shorts (256 B)
#define P0SZ (PR2 * PLD)        // 8448 shorts per panel

typedef __attribute__((ext_vector_type(8))) short short8;
typedef __attribute__((ext_vector_type(4))) float floatx4;
typedef __attribute__((ext_vector_type(16))) float floatx16;
typedef __attribute__((ext_vector_type(8))) unsigned short ushort8v;
typedef __attribute__((ext_vector_type(4))) unsigned short ushort4v;

static __device__ __forceinline__ unsigned short f2bf(float f) {
    unsigned int u = __float_as_uint(f);
    return (unsigned short)((u + 0x7FFF + ((u >> 16) & 1)) >> 16);  // RTNE
}

// ---------------------------------------------------------------------------
// pack: fragment-pack weights (identical to round 11, verified).
// ---------------------------------------------------------------------------
__global__ __launch_bounds__(256) void pack_kernel(
    const float* __restrict__ U, const float* __restrict__ V,
    const float* __restrict__ Bw,
    unsigned short* __restrict__ WcTp, unsigned short* __restrict__ UTp)
{
    const int blk = blockIdx.x;
    const int t   = threadIdx.x;

    if (blk < 96) {
        const int gk = blk >> 3;            // 0..11 = g*3 + k
        const int g  = gk / 3, k = gk % 3;
        const int ks = t >> 5;              // 0..7
        const int f  = (blk & 7) * 32 + (t & 31);
        unsigned short* dst = WcTp + ((size_t)(gk * 8 + ks) * 256 + f) * 16;
        #pragma unroll
        for (int c = 0; c < 16; ++c) {
            const int ch = g * 128 + ks * 16 + c;
            const float v = (ch < DIN)
                ? Bw[(size_t)ch * KF + k * NF + f]
                : V[(size_t)(ch - DIN) * KF + k * NF + f];
            dst[c] = f2bf(v);
        }
    } else {
        const int bb = blk - 96;            // 0..15
        const int kk = bb >> 1;             // 0..7
        const int e0 = (bb & 1) * 128;
        #pragma unroll
        for (int it = 0; it < 2; ++it) {
            const int p    = t + it * 256;  // 0..511
            const int e    = e0 + (p >> 2);
            const int quad = p & 3;
            unsigned short* dst =
                UTp + ((size_t)(kk * 256 + e) * 4 + quad) * 8;
            #pragma unroll
            for (int c = 0; c < 8; ++c) {
                const int d = kk * 32 + quad * 8 + c;
                dst[c] = f2bf(U[(size_t)d * DIN + e]);
            }
        }
    }
}

// ---------------------------------------------------------------------------
// fused kernel. Grid 512 x 256. LDS 67584 B -> 2 blocks/CU.
// ---------------------------------------------------------------------------
__global__ __launch_bounds__(256, 2) void fused_kernel(
    const float* __restrict__ x, const float* __restrict__ z,
    const unsigned short* __restrict__ UTp,
    const unsigned short* __restrict__ WcTp,
    const float* __restrict__ bias, float* __restrict__ out)
{
    __shared__ __align__(16) unsigned short lds[4 * P0SZ];   // 67584 B

    const int tid  = threadIdx.x;
    const int lane = tid & 63;
    const int wave = tid >> 6;               // 0..3
    const int quad = lane >> 4, l16 = lane & 15;
    const int l32  = lane & 31, hi  = lane >> 5;

    const int bid = blockIdx.x;
    const int b   = bid >> 3;
    const int l0  = (bid & 7) * 64;

    // ---- G-stream fragment loaders (UTp, coalesced) -----------------------
    short8 uA[4], uB[4];
    auto loadU = [&](int kk, short8 (&buf)[4]) {
        #pragma unroll
        for (int q = 0; q < 4; ++q) {
            const int e = q * 64 + wave * 16 + l16;
            buf[q] = *(const short8*)
                &UTp[((size_t)(kk * 256 + e) * 4 + quad) * 8];
        }
    };

    // issue first G fragments immediately: latency hides under phase X
    loadU(0, uA);

    // ---------------- phase X: x -> P0, P1 (bf16, swizzled) ----------------
    #pragma unroll
    for (int p = 0; p < 2; ++p) {
        unsigned short* P = lds + (size_t)p * P0SZ;
        #pragma unroll
        for (int it = 0; it < 5; ++it) {
            const int idx = tid + it * 256;
            if (idx < PR2 * 16) {
                const int row = idx >> 4, u = idx & 15;
                const int l = l0 - 1 + row;
                ushort8v h = {};
                if (l >= 0 && l < SEQL) {
                    const float* xp =
                        x + ((size_t)b * SEQL + l) * DIN + p * 128 + u * 8;
                    const float4 v0 = *(const float4*)xp;
                    const float4 v1 = *(const float4*)(xp + 4);
                    h[0] = f2bf(v0.x); h[1] = f2bf(v0.y);
                    h[2] = f2bf(v0.z); h[3] = f2bf(v0.w);
                    h[4] = f2bf(v1.x); h[5] = f2bf(v1.y);
                    h[6] = f2bf(v1.z); h[7] = f2bf(v1.w);
                }
                *(ushort8v*)&P[row * PLD + ((u ^ (row & 15)) << 3)] = h;
            }
        }
    }
    __syncthreads();                              // barrier 1 of 2

    // ---------------- phase G: Y = (x@U)*sigmoid(z), operand-swapped -------
    // accY = mfma(A = UTp fragment (reg ping-pong), B = x fragment (LDS)).
    // D[e][xrow]: lane holds e = q*64+wave*16+quad*4+reg, xrow = i*16+l16.
    floatx4 accY[4][5] = {};
    {
        auto computeG = [&](int kk, const short8 (&buf)[4]) {
            const unsigned short* P = lds + (size_t)(kk >> 2) * P0SZ;
            const int ux = (kk & 3) * 4 + quad;
            __builtin_amdgcn_s_setprio(1);
            #pragma unroll
            for (int i = 0; i < 5; ++i) {
                const int row = i * 16 + l16; // rows>=66 garbage, masked later
                const short8 xf = *(const short8*)
                    &P[row * PLD + ((ux ^ (row & 15)) << 3)];
                #pragma unroll
                for (int q = 0; q < 4; ++q)
                    accY[q][i] = __builtin_amdgcn_mfma_f32_16x16x32_bf16(
                        buf[q], xf, accY[q][i], 0, 0, 0);
            }
            __builtin_amdgcn_s_setprio(0);
        };
        #pragma unroll 1
        for (int kb = 0; kb < 4; ++kb) {
            const int kk = kb * 2;
            loadU(kk + 1, uB);
            computeG(kk, uA);
            if (kk + 2 < 8) loadU(kk + 2, uA);
            computeG(kk + 1, uB);
        }
    }

    // ---- conv-stream fragment loaders (WcTp, coalesced) -------------------
    short8 bA[16], bB[16];
    auto loadB = [&](int r, short8 (&buf)[16]) {
        const int gg = r / 3, k = r - gg * 3;
        const int g  = (gg + (bid & 3)) & 3;
        const unsigned short* gW = WcTp + (size_t)(g * 3 + k) * 8 * 4096;
        #pragma unroll
        for (int ks = 0; ks < 8; ++ks)
            #pragma unroll
            for (int j = 0; j < 2; ++j) {
                const int f = wave * 64 + j * 32 + l32;
                buf[ks * 2 + j] = *(const short8*)
                    &gW[(size_t)ks * 4096 + (size_t)f * 16 + hi * 8];
            }
    };

    // issue first conv region now: latency hides under Y-epilogue + barrier
    loadB(0, bA);

    // Y epilogue: lane holds 4 consecutive e -> b64 writes into P2/P3.
    #pragma unroll
    for (int q = 0; q < 4; ++q) {
        const int e0 = q * 64 + wave * 16 + quad * 4;    // 0..252
        unsigned short* PY = lds + (size_t)(2 + (q >> 1)) * P0SZ;
        const int c0 = e0 & 127;
        float zf[4];
        #pragma unroll
        for (int r2 = 0; r2 < 4; ++r2)
            zf[r2] = 1.0f / (1.0f + expf(-z[(size_t)b * DIN + e0 + r2]));
        const int u = c0 >> 3;
        #pragma unroll
        for (int i = 0; i < 5; ++i) {
            const int xrow = i * 16 + l16;
            if (xrow < PR2) {
                ushort4v h;
                #pragma unroll
                for (int r2 = 0; r2 < 4; ++r2)
                    h[r2] = f2bf(accY[q][i][r2] * zf[r2]);
                *(ushort4v*)&PY[xrow * PLD + ((u ^ (xrow & 15)) << 3) +
                                (c0 & 7)] = h;
            }
        }
    }
    __syncthreads();                              // barrier 2 of 2

    // ---------------- conv: 12 regions, register ping-pong, barrier-free ---
    floatx16 acc2[2][2] = {};
    {
        auto computeB = [&](int r, const short8 (&buf)[16]) {
            const int gg = r / 3, k = r - gg * 3;
            const int g  = (gg + (bid & 3)) & 3;
            const unsigned short* P = lds + (size_t)g * P0SZ;
            __builtin_amdgcn_s_setprio(1);
            #pragma unroll
            for (int ks = 0; ks < 8; ++ks) {
                short8 af[2];
                const int ua = ks * 2 + hi;
                #pragma unroll
                for (int i = 0; i < 2; ++i) {
                    const int m = i * 32 + l32 + k;          // 0..65
                    af[i] = *(const short8*)
                        &P[m * PLD + ((ua ^ (m & 15)) << 3)];
                }
                #pragma unroll
                for (int i = 0; i < 2; ++i)
                    #pragma unroll
                    for (int j = 0; j < 2; ++j)
                        acc2[i][j] = __builtin_amdgcn_mfma_f32_32x32x16_bf16(
                            af[i], buf[ks * 2 + j], acc2[i][j], 0, 0, 0);
            }
            __builtin_amdgcn_s_setprio(0);
        };
        #pragma unroll 1
        for (int rr = 0; rr < 6; ++rr) {
            const int r = rr * 2;
            loadB(r + 1, bB);
            computeB(r, bA);
            if (r + 2 < 12) loadB(r + 2, bA);
            computeB(r + 1, bB);
        }
    }

    // ---------------- epilogue: bias + relu -> out -------------------------
    #pragma unroll
    for (int j = 0; j < 2; ++j) {
        const int f  = wave * 64 + j * 32 + l32;
        const float bv = bias[f];
        #pragma unroll
        for (int i = 0; i < 2; ++i) {
            #pragma unroll
            for (int reg = 0; reg < 16; ++reg) {
                const int rowl = i * 32 + (reg & 3) + 8 * (reg >> 2) + 4 * hi;
                const float v = acc2[i][j][reg] + bv;
                out[((size_t)b * SEQL + l0 + rowl) * NF + f] = fmaxf(v, 0.0f);
            }
        }
    }
}

extern "C" void kernel_launch(void* const* d_in, const int* in_sizes, int n_in,
                              void* d_out, int out_size, void* d_ws, size_t ws_size,
                              hipStream_t stream) {
    const float* x    = (const float*)d_in[0];
    const float* z    = (const float*)d_in[1];
    const float* U    = (const float*)d_in[2];
    const float* V    = (const float*)d_in[3];
    const float* Bw   = (const float*)d_in[4];
    const float* bias = (const float*)d_in[5];

    unsigned short* WcTp = (unsigned short*)d_ws;            // 393216 shorts
    unsigned short* UTp  = WcTp + (size_t)12 * 8 * 256 * 16; // 65536 shorts
    float* out = (float*)d_out;

    pack_kernel<<<dim3(112), 256, 0, stream>>>(U, V, Bw, WcTp, UTp);
    fused_kernel<<<dim3(512), 256, 0, stream>>>(x, z, UTp, WcTp, bias, out);
}